// Round 6
// baseline (60.855 us; speedup 1.0000x reference)
//
#include <hip/hip_runtime.h>

// Chamfer distance via MFMA, N=M=16384, D=3, f32.
// min_j dist(p,q_j) = -2 * ( max_j (dot(p,q_j) - 0.5|q_j|^2) - 0.5|p|^2 ), clamped >= 0.
// dot computed EXACTLY (to fp32 rounding) on the bf16 matrix pipe: 3-way bf16
// split per coord (hi/mid/lo = 24 mantissa bits), 9 cross-products per dim in
// K-slots (27), slots 27..29 carry -0.5|q|^2 against 1.0. One
// mfma_f32_16x16x32_bf16 = 16 q x 16 owners of (dot - 0.5|q|^2).
// R5 vs R4 (51us, MfmaUtil 26.5% -> pipe fed only 25% of the time):
//  - all 8 MFMAs issue into named d0..d7 BEFORE any v_max3 (covers MFMA
//    result latency; no per-MFMA hazard stalls)
//  - register ping-pong prefetch of next A-tile (hides ~120cy LDS latency)
//  - no min-waves launch bound (natural ~90 VGPR -> 5 waves/EU; 5x32KB LDS
//    = 160KB exactly fills a CU)
//  - waves start the t-loop at staggered offsets (max is order-independent)
//    to break intra-block phase lockstep.

typedef short bf16x8 __attribute__((ext_vector_type(8)));  // 8 bf16 = 4 VGPR
typedef float f32x4 __attribute__((ext_vector_type(4)));

#define NPTS   16384
#define TPB    256
#define OT     8                  // owner 16-tiles per wave -> 128 owners/wave
#define OPW    (OT * 16)          // 128
#define OPB    (OPW * 4)          // 512 owners per block (4 waves)
#define SLICES 32                 // q slices
#define QSL    (NPTS / SLICES)    // 512 q per slice (32 KB LDS)
#define NT     (QSL / 16)         // 32 A-tiles per slice

__device__ __forceinline__ unsigned short f2b(float f) {  // fp32 -> bf16 RNE
    union { float f; unsigned u; } a; a.f = f;
    return (unsigned short)((a.u + 0x7FFFu + ((a.u >> 16) & 1u)) >> 16);
}
__device__ __forceinline__ float b2f(unsigned short b) {
    union { unsigned u; float f; } a; a.u = ((unsigned)b) << 16;
    return a.f;
}

// Per point, build the A-role (q-side) and B-role (owner-side) 32-slot bf16
// k-vectors, the fp32 0.5|v|^2, and init the min array (every call: graph
// replay must be deterministic).
__global__ __launch_bounds__(TPB) void cd_prep(
        const float* __restrict__ x, const float* __restrict__ y,
        unsigned short* __restrict__ xA, unsigned short* __restrict__ xB,
        unsigned short* __restrict__ yA, unsigned short* __restrict__ yB,
        float* __restrict__ xh, float* __restrict__ yh,
        unsigned* __restrict__ minx, unsigned* __restrict__ miny, int n, int m) {
    int i = blockIdx.x * TPB + threadIdx.x;
    if (i >= n + m) return;
    const float* src = (i < n) ? x : y;
    int k = (i < n) ? i : i - n;
    unsigned short* A = (i < n) ? xA : yA;
    unsigned short* B = (i < n) ? xB : yB;
    float* h = (i < n) ? xh : yh;
    unsigned* mn = (i < n) ? minx : miny;

    float v[3] = { src[3 * k], src[3 * k + 1], src[3 * k + 2] };
    unsigned short sp[3][3];  // [dim][split]
#pragma unroll
    for (int d = 0; d < 3; ++d) {
        float r = v[d];
        sp[d][0] = f2b(r); r -= b2f(sp[d][0]);
        sp[d][1] = f2b(r); r -= b2f(sp[d][1]);
        sp[d][2] = f2b(r);
    }
    float half = 0.5f * (v[0] * v[0] + v[1] * v[1] + v[2] * v[2]);
    unsigned short ss[3];
    { float r = -half;
      ss[0] = f2b(r); r -= b2f(ss[0]);
      ss[1] = f2b(r); r -= b2f(ss[1]);
      ss[2] = f2b(r); }

    unsigned short Av[32], Bv[32];
#pragma unroll
    for (int j = 0; j < 32; ++j) { Av[j] = 0; Bv[j] = 0; }
#pragma unroll
    for (int d = 0; d < 3; ++d)
#pragma unroll
        for (int a = 0; a < 3; ++a)        // owner-split index
#pragma unroll
            for (int t = 0; t < 3; ++t) {  // q-split index
                Av[d * 9 + a * 3 + t] = sp[d][t];  // q side: repeat over a
                Bv[d * 9 + a * 3 + t] = sp[d][a];  // p side: repeat over t
            }
#pragma unroll
    for (int a = 0; a < 3; ++a) { Av[27 + a] = ss[a]; Bv[27 + a] = 0x3F80; }  // 1.0

    unsigned* Ao = (unsigned*)(A + (size_t)k * 32);
    unsigned* Bo = (unsigned*)(B + (size_t)k * 32);
#pragma unroll
    for (int j = 0; j < 16; ++j) {
        Ao[j] = (unsigned)Av[2 * j] | ((unsigned)Av[2 * j + 1] << 16);
        Bo[j] = (unsigned)Bv[2 * j] | ((unsigned)Bv[2 * j + 1] << 16);
    }
    h[k] = half;
    mn[k] = 0x7f800000u;  // +inf
}

// blockIdx = (owner-block, q-slice, direction). Block stages its 512-q
// A-slice into LDS (XOR-swizzled), then each wave runs 128 resident owners x
// 32 A-tiles: per tile 1 prefetched ds_read_b128 + 8 MFMA burst + 16 v_max3.
// Slice partials via uint atomicMin (distances >= 0: float order == uint bit
// order).
__global__ __launch_bounds__(TPB) void cd_pass(
        const unsigned short* __restrict__ xA, const unsigned short* __restrict__ xB,
        const unsigned short* __restrict__ yA, const unsigned short* __restrict__ yB,
        const float* __restrict__ xh, const float* __restrict__ yh,
        unsigned* __restrict__ minx, unsigned* __restrict__ miny) {
    __shared__ __align__(16) char As[QSL * 64];

    const int lane = threadIdx.x & 63;
    const int wave = threadIdx.x >> 6;
    const int r = lane & 15, g = lane >> 4;

    const unsigned short* Aq; const unsigned short* Bp;
    const float* hs; unsigned* out;
    if (blockIdx.z == 0) { Aq = yA; Bp = xB; hs = xh; out = minx; }  // owners=x
    else                 { Aq = xA; Bp = yB; hs = yh; out = miny; }  // owners=y

    // Stage A slice -> LDS (swizzled). 2048 16B-chunks, 256 threads, 8 iters.
    const int q0 = blockIdx.y * QSL;
#pragma unroll
    for (int it = 0; it < (QSL * 4) / TPB; ++it) {
        int idx = it * TPB + threadIdx.x;
        int row = idx >> 2, gg = idx & 3;
        float4 v = *(const float4*)(Aq + (size_t)(q0 + row) * 32 + gg * 8);
        *(float4*)(As + ((row * 64 + gg * 16) ^ ((row & 7) << 4))) = v;
    }
    __syncthreads();

    const int obase = blockIdx.x * OPB + wave * OPW;
    bf16x8 b[OT];
    float mx[OT];
#pragma unroll
    for (int o = 0; o < OT; ++o) {
        b[o] = *(const bf16x8*)(Bp + (size_t)(obase + o * 16 + r) * 32 + g * 8);
        mx[o] = -INFINITY;
    }

    // Per-lane LDS base: row = tt*16 + r, so addr = tt*1024 + lbase.
    const int lbase = (r * 64 + g * 16) ^ ((r & 7) << 4);
    const f32x4 zero = {0.f, 0.f, 0.f, 0.f};

    int tt = wave * (NT / 4);  // staggered start per wave (max is order-free)
    bf16x8 aCur = *(const bf16x8*)(As + lbase + tt * 1024);
#pragma unroll 4
    for (int i = 0; i < NT; ++i) {
        const int tn = (tt + 1) & (NT - 1);
        bf16x8 aNxt = *(const bf16x8*)(As + lbase + tn * 1024);  // prefetch

        // 8-MFMA burst into distinct named regs (no VALU consumer in between:
        // issue window ~39cy covers MFMA result latency).
        f32x4 d0 = __builtin_amdgcn_mfma_f32_16x16x32_bf16(aCur, b[0], zero, 0, 0, 0);
        f32x4 d1 = __builtin_amdgcn_mfma_f32_16x16x32_bf16(aCur, b[1], zero, 0, 0, 0);
        f32x4 d2 = __builtin_amdgcn_mfma_f32_16x16x32_bf16(aCur, b[2], zero, 0, 0, 0);
        f32x4 d3 = __builtin_amdgcn_mfma_f32_16x16x32_bf16(aCur, b[3], zero, 0, 0, 0);
        f32x4 d4 = __builtin_amdgcn_mfma_f32_16x16x32_bf16(aCur, b[4], zero, 0, 0, 0);
        f32x4 d5 = __builtin_amdgcn_mfma_f32_16x16x32_bf16(aCur, b[5], zero, 0, 0, 0);
        f32x4 d6 = __builtin_amdgcn_mfma_f32_16x16x32_bf16(aCur, b[6], zero, 0, 0, 0);
        f32x4 d7 = __builtin_amdgcn_mfma_f32_16x16x32_bf16(aCur, b[7], zero, 0, 0, 0);

        mx[0] = fmaxf(mx[0], fmaxf(d0[0], d0[1]));
        mx[0] = fmaxf(mx[0], fmaxf(d0[2], d0[3]));
        mx[1] = fmaxf(mx[1], fmaxf(d1[0], d1[1]));
        mx[1] = fmaxf(mx[1], fmaxf(d1[2], d1[3]));
        mx[2] = fmaxf(mx[2], fmaxf(d2[0], d2[1]));
        mx[2] = fmaxf(mx[2], fmaxf(d2[2], d2[3]));
        mx[3] = fmaxf(mx[3], fmaxf(d3[0], d3[1]));
        mx[3] = fmaxf(mx[3], fmaxf(d3[2], d3[3]));
        mx[4] = fmaxf(mx[4], fmaxf(d4[0], d4[1]));
        mx[4] = fmaxf(mx[4], fmaxf(d4[2], d4[3]));
        mx[5] = fmaxf(mx[5], fmaxf(d5[0], d5[1]));
        mx[5] = fmaxf(mx[5], fmaxf(d5[2], d5[3]));
        mx[6] = fmaxf(mx[6], fmaxf(d6[0], d6[1]));
        mx[6] = fmaxf(mx[6], fmaxf(d6[2], d6[3]));
        mx[7] = fmaxf(mx[7], fmaxf(d7[0], d7[1]));
        mx[7] = fmaxf(mx[7], fmaxf(d7[2], d7[3]));

        aCur = aNxt;
        tt = tn;
    }

#pragma unroll
    for (int o = 0; o < OT; ++o) {
        float vv = mx[o];
        vv = fmaxf(vv, __shfl_xor(vv, 16, 64));
        vv = fmaxf(vv, __shfl_xor(vv, 32, 64));
        if (lane < 16) {
            int id = obase + o * 16 + lane;
            float dmin = fmaxf(0.0f, 2.0f * (hs[id] - vv));
            atomicMin(&out[id], __float_as_uint(dmin));
        }
    }
}

// Single-block final reduction: mean of minx[N] ++ miny[M].
__global__ __launch_bounds__(1024) void cd_reduce(const uint4* __restrict__ minx,
                                                  const uint4* __restrict__ miny,
                                                  float* __restrict__ out, int n, int mm) {
    float s = 0.0f;
    for (int i = threadIdx.x; i < n / 4; i += 1024) {
        uint4 v = minx[i];
        s += __uint_as_float(v.x) + __uint_as_float(v.y) +
             __uint_as_float(v.z) + __uint_as_float(v.w);
    }
    for (int i = threadIdx.x; i < mm / 4; i += 1024) {
        uint4 v = miny[i];
        s += __uint_as_float(v.x) + __uint_as_float(v.y) +
             __uint_as_float(v.z) + __uint_as_float(v.w);
    }
    for (int off = 32; off >= 1; off >>= 1) s += __shfl_down(s, off, 64);
    __shared__ float wsum[16];
    int wave = threadIdx.x >> 6;
    int lane = threadIdx.x & 63;
    if (lane == 0) wsum[wave] = s;
    __syncthreads();
    if (threadIdx.x == 0) {
        float t = 0.0f;
        for (int w = 0; w < 16; ++w) t += wsum[w];
        out[0] = t / (float)(n + mm);
    }
}

extern "C" void kernel_launch(void* const* d_in, const int* in_sizes, int n_in,
                              void* d_out, int out_size, void* d_ws, size_t ws_size,
                              hipStream_t stream) {
    const float* x = (const float*)d_in[0];
    const float* y = (const float*)d_in[1];
    const int N = in_sizes[0] / 3;  // 16384
    const int M = in_sizes[1] / 3;  // 16384

    unsigned short* xA = (unsigned short*)d_ws;     // N*32 bf16
    unsigned short* xB = xA + (size_t)N * 32;       // N*32
    unsigned short* yA = xB + (size_t)N * 32;       // M*32
    unsigned short* yB = yA + (size_t)M * 32;       // M*32
    float* xh = (float*)(yB + (size_t)M * 32);      // N f32
    float* yh = xh + N;                             // M f32
    unsigned* minx = (unsigned*)(yh + M);           // N uint
    unsigned* miny = minx + N;                      // M uint
    float* out = (float*)d_out;

    cd_prep<<<(N + M + TPB - 1) / TPB, TPB, 0, stream>>>(x, y, xA, xB, yA, yB,
                                                         xh, yh, minx, miny, N, M);

    // grid: (owner blocks, q slices, direction) = (32, 32, 2) = 2048 blocks
    cd_pass<<<dim3(NPTS / OPB, SLICES, 2), TPB, 0, stream>>>(xA, xB, yA, yB,
                                                             xh, yh, minx, miny);

    cd_reduce<<<1, 1024, 0, stream>>>((const uint4*)minx, (const uint4*)miny, out, N, M);
}